// Round 1
// baseline (721.404 us; speedup 1.0000x reference)
//
#include <hip/hip_runtime.h>

// LinearAttention fused pipeline, fp32 baseline.
// x:(16,256,64,64) w_qkv:(768,256) w_out:(256,256) b_out:(256) gamma/beta:(256)
// N = 4096 spatial, HEADS=8, DIM_HEAD=32, groups=32 (8 ch/group).
//
// Workspace layout (floats):
//   qkv   : [16][768][4096]  (q slot reused for attn-out, k slot reused for linear-out)
//   ctxp  : [16*8][4 splits][1024]
//   stats : [16*32] float2 (mean, inv_std)

// ---------------- GEMM: Y[b][o][n] = sum_c W[o][c] * X[b][c][n] (+bias) ---------
__global__ __launch_bounds__(256) void gemm_ocn(
    const float* __restrict__ W, const float* __restrict__ X,
    float* __restrict__ Y, const float* __restrict__ bias,
    long xbs, long ybs) {
  int b = blockIdx.z;
  int ot = blockIdx.y * 64;
  int nt = blockIdx.x * 64;
  const float* Xb = X + (long)b * xbs;
  float* Yb = Y + (long)b * ybs;
  __shared__ float As[16][65];
  __shared__ float Bs[16][65];
  int tid = threadIdx.x;
  int ty = tid >> 4, tx = tid & 15;
  float acc[4][4] = {};
  for (int k0 = 0; k0 < 256; k0 += 16) {
#pragma unroll
    for (int l = 0; l < 4; ++l) {
      int idx = tid + l * 256;
      int i = idx >> 4, kk = idx & 15;
      As[kk][i] = W[(ot + i) * 256 + k0 + kk];
    }
#pragma unroll
    for (int l = 0; l < 4; ++l) {
      int idx = tid + l * 256;
      int kk = idx >> 6, j = idx & 63;
      Bs[kk][j] = Xb[(long)(k0 + kk) * 4096 + nt + j];
    }
    __syncthreads();
#pragma unroll
    for (int kk = 0; kk < 16; ++kk) {
      float a[4], bb[4];
#pragma unroll
      for (int ii = 0; ii < 4; ++ii) a[ii] = As[kk][ty + 16 * ii];
#pragma unroll
      for (int jj = 0; jj < 4; ++jj) bb[jj] = Bs[kk][tx + 16 * jj];
#pragma unroll
      for (int ii = 0; ii < 4; ++ii)
#pragma unroll
        for (int jj = 0; jj < 4; ++jj)
          acc[ii][jj] += a[ii] * bb[jj];
    }
    __syncthreads();
  }
#pragma unroll
  for (int ii = 0; ii < 4; ++ii) {
    int o = ot + ty + 16 * ii;
    float bv = bias ? bias[o] : 0.f;
#pragma unroll
    for (int jj = 0; jj < 4; ++jj)
      Yb[(long)o * 4096 + nt + tx + 16 * jj] = acc[ii][jj] + bv;
  }
}

// ---------------- q softmax over DIM_HEAD (32, stride 4096) --------------------
__global__ __launch_bounds__(256) void softmax_q(float* __restrict__ qkv) {
  int n = blockIdx.x * 256 + threadIdx.x;
  int h = blockIdx.y;
  int b = blockIdx.z;
  float* base = qkv + ((long)b * 768 + h * 32) * 4096 + n;
  float v[32];
  float m = -1e30f;
#pragma unroll
  for (int d = 0; d < 32; ++d) { v[d] = base[(long)d * 4096]; m = fmaxf(m, v[d]); }
  float s = 0.f;
#pragma unroll
  for (int d = 0; d < 32; ++d) { v[d] = __expf(v[d] - m); s += v[d]; }
  float inv = 1.f / s;
#pragma unroll
  for (int d = 0; d < 32; ++d) base[(long)d * 4096] = v[d] * inv;
}

// ---------------- k softmax over n (4096, contiguous row) ----------------------
__global__ __launch_bounds__(256) void softmax_k(float* __restrict__ qkv) {
  int b = blockIdx.x >> 8;
  int r = blockIdx.x & 255;
  float* p = qkv + ((long)b * 768 + 256 + r) * 4096;
  int tid = threadIdx.x;
  int wave = tid >> 6, lane = tid & 63;
  float4 vv[4];
  float m = -1e30f;
#pragma unroll
  for (int l = 0; l < 4; ++l) {
    vv[l] = reinterpret_cast<float4*>(p)[tid + l * 256];
    m = fmaxf(m, fmaxf(fmaxf(vv[l].x, vv[l].y), fmaxf(vv[l].z, vv[l].w)));
  }
  __shared__ float redm[4], reds[4];
#pragma unroll
  for (int off = 32; off >= 1; off >>= 1) m = fmaxf(m, __shfl_xor(m, off));
  if (lane == 0) redm[wave] = m;
  __syncthreads();
  m = fmaxf(fmaxf(redm[0], redm[1]), fmaxf(redm[2], redm[3]));
  float s = 0.f;
#pragma unroll
  for (int l = 0; l < 4; ++l) {
    vv[l].x = __expf(vv[l].x - m); vv[l].y = __expf(vv[l].y - m);
    vv[l].z = __expf(vv[l].z - m); vv[l].w = __expf(vv[l].w - m);
    s += vv[l].x + vv[l].y + vv[l].z + vv[l].w;
  }
#pragma unroll
  for (int off = 32; off >= 1; off >>= 1) s += __shfl_xor(s, off);
  if (lane == 0) reds[wave] = s;
  __syncthreads();
  s = reds[0] + reds[1] + reds[2] + reds[3];
  float inv = 1.f / s;
#pragma unroll
  for (int l = 0; l < 4; ++l) {
    vv[l].x *= inv; vv[l].y *= inv; vv[l].z *= inv; vv[l].w *= inv;
    reinterpret_cast<float4*>(p)[tid + l * 256] = vv[l];
  }
}

// ---------------- context[d][e] = sum_n k[d][n]*v[e][n] (n-split x4) -----------
__global__ __launch_bounds__(256) void context_partial(
    const float* __restrict__ qkv, float* __restrict__ ctxp) {
  int split = blockIdx.x;
  int h = blockIdx.y;
  int b = blockIdx.z;
  const float* kbase = qkv + ((long)b * 768 + 256 + h * 32) * 4096;
  const float* vbase = qkv + ((long)b * 768 + 512 + h * 32) * 4096;
  __shared__ float ks[32][129];
  __shared__ float vs[32][129];
  int tid = threadIdx.x;
  int d = tid >> 3;
  int e4 = (tid & 7) * 4;
  float acc[4] = {};
  for (int n0 = split * 1024; n0 < split * 1024 + 1024; n0 += 128) {
#pragma unroll
    for (int l = 0; l < 4; ++l) {
      int idx4 = tid + l * 256;
      int row = idx4 >> 5, c4 = (idx4 & 31) * 4;
      *(float4*)&ks[row][c4] = *(const float4*)&kbase[(long)row * 4096 + n0 + c4];
      *(float4*)&vs[row][c4] = *(const float4*)&vbase[(long)row * 4096 + n0 + c4];
    }
    __syncthreads();
#pragma unroll 8
    for (int nn = 0; nn < 128; ++nn) {
      float kv = ks[d][nn];
#pragma unroll
      for (int j = 0; j < 4; ++j) acc[j] += kv * vs[e4 + j][nn];
    }
    __syncthreads();
  }
  float* dst = ctxp + ((long)(b * 8 + h) * 4 + split) * 1024;
#pragma unroll
  for (int j = 0; j < 4; ++j) dst[d * 32 + e4 + j] = acc[j];
}

// ---------------- out[e][n] = sum_d ctx[d][e]*q[d][n], in-place into q slot ----
__global__ __launch_bounds__(256) void attn_out(
    float* __restrict__ qkv, const float* __restrict__ ctxp) {
  int nchunk = blockIdx.x;
  int h = blockIdx.y;
  int b = blockIdx.z;
  __shared__ float cs[1024];
  int tid = threadIdx.x;
  const float* src = ctxp + (long)(b * 8 + h) * 4 * 1024;
#pragma unroll
  for (int l = 0; l < 4; ++l) {
    int i = tid + l * 256;
    cs[i] = src[i] + src[i + 1024] + src[i + 2048] + src[i + 3072];
  }
  __syncthreads();
  int n = nchunk * 256 + tid;
  float* qb = qkv + ((long)b * 768 + h * 32) * 4096 + n;
  float qr[32];
#pragma unroll
  for (int d = 0; d < 32; ++d) qr[d] = qb[(long)d * 4096];
#pragma unroll
  for (int e = 0; e < 32; ++e) {
    float s = 0.f;
#pragma unroll
    for (int d = 0; d < 32; ++d) s += cs[d * 32 + e] * qr[d];
    qb[(long)e * 4096] = s;
  }
}

// ---------------- groupnorm stats: mean/inv_std per (b, group) -----------------
__global__ __launch_bounds__(256) void gn_stats(
    const float* __restrict__ qkv, float2* __restrict__ stats) {
  int g = blockIdx.x;
  int b = blockIdx.y;
  const float* base = qkv + ((long)b * 768 + 256 + g * 8) * 4096;
  int tid = threadIdx.x;
  float s = 0.f, ss = 0.f;
#pragma unroll 4
  for (int l = 0; l < 32; ++l) {
    float4 v = ((const float4*)base)[tid + l * 256];
    s += v.x + v.y + v.z + v.w;
    ss += v.x * v.x + v.y * v.y + v.z * v.z + v.w * v.w;
  }
  int wave = tid >> 6, lane = tid & 63;
#pragma unroll
  for (int off = 32; off >= 1; off >>= 1) { s += __shfl_xor(s, off); ss += __shfl_xor(ss, off); }
  __shared__ float rs[4], rss[4];
  if (lane == 0) { rs[wave] = s; rss[wave] = ss; }
  __syncthreads();
  if (tid == 0) {
    s = rs[0] + rs[1] + rs[2] + rs[3];
    ss = rss[0] + rss[1] + rss[2] + rss[3];
    float mean = s * (1.f / 32768.f);
    float var = ss * (1.f / 32768.f) - mean * mean;
    stats[b * 32 + g] = make_float2(mean, rsqrtf(var + 1e-6f));
  }
}

// ---------------- normalize + affine + residual --------------------------------
__global__ __launch_bounds__(256) void final_out(
    const float* __restrict__ qkv, const float* __restrict__ x,
    const float2* __restrict__ stats,
    const float* __restrict__ gamma, const float* __restrict__ beta,
    float* __restrict__ out) {
  long idx4 = (long)blockIdx.x * 256 + threadIdx.x;  // float4 units, 4194304 total
  long e0 = idx4 * 4;
  int b = (int)(e0 >> 20);
  int rem = (int)(e0 & ((1 << 20) - 1));
  int c = rem >> 12;
  float2 st = stats[b * 32 + (c >> 3)];
  float ga = gamma[c] * st.y;
  float be = beta[c] - st.x * ga;
  float4 l = *(const float4*)&qkv[((long)b * 768 + 256 + c) * 4096 + (rem & 4095)];
  float4 xv = *(const float4*)&x[e0];
  float4 o;
  o.x = l.x * ga + be + xv.x;
  o.y = l.y * ga + be + xv.y;
  o.z = l.z * ga + be + xv.z;
  o.w = l.w * ga + be + xv.w;
  *(float4*)&out[e0] = o;
}

extern "C" void kernel_launch(void* const* d_in, const int* in_sizes, int n_in,
                              void* d_out, int out_size, void* d_ws, size_t ws_size,
                              hipStream_t stream) {
  const float* x     = (const float*)d_in[0];
  const float* w_qkv = (const float*)d_in[1];
  const float* w_out = (const float*)d_in[2];
  const float* b_out = (const float*)d_in[3];
  const float* gamma = (const float*)d_in[4];
  const float* beta  = (const float*)d_in[5];
  float* out = (float*)d_out;

  float* qkv  = (float*)d_ws;                       // 16*768*4096 floats
  float* ctxp = qkv + 16l * 768 * 4096;             // 16*8*4*1024 floats
  float2* stats = (float2*)(ctxp + 16l * 8 * 4 * 1024);  // 512 float2

  // 1) qkv = w_qkv @ x   (per batch)
  gemm_ocn<<<dim3(64, 12, 16), 256, 0, stream>>>(
      w_qkv, x, qkv, nullptr, 256l * 4096, 768l * 4096);
  // 2) q softmax over DIM_HEAD
  softmax_q<<<dim3(16, 8, 16), 256, 0, stream>>>(qkv);
  // 3) k softmax over n
  softmax_k<<<dim3(4096), 256, 0, stream>>>(qkv);
  // 4) context = k @ v^T (n-split x4)
  context_partial<<<dim3(4, 8, 16), 256, 0, stream>>>(qkv, ctxp);
  // 5) attn = ctx^T @ q  (in-place into q slot)
  attn_out<<<dim3(16, 8, 16), 256, 0, stream>>>(qkv, ctxp);
  // 6) lin = w_out @ attn + b_out  (into k slot)
  gemm_ocn<<<dim3(64, 4, 16), 256, 0, stream>>>(
      w_out, qkv, qkv + 256l * 4096, b_out, 768l * 4096, 768l * 4096);
  // 7) groupnorm stats
  gn_stats<<<dim3(32, 16), 256, 0, stream>>>(qkv, stats);
  // 8) normalize + residual
  final_out<<<dim3(16384), 256, 0, stream>>>(qkv, x, stats, gamma, beta, out);
}

// Round 2
// 191.624 us; speedup vs baseline: 3.7647x; 3.7647x over previous
//
#include <hip/hip_runtime.h>

// LinearAttention, bf16 MFMA pipeline.
// x:(16,256,64,64) fp32, w_qkv:(768,256), w_out:(256,256), b_out:(256), gamma/beta:(256)
// N=4096, HEADS=8, DIM_HEAD=32, groups=32.
//
// Pipeline:
//  1. cast_to_bf16: w_qkv -> bf16
//  2. cast_transpose_x: x -> xt[b][n][c] bf16
//  3. gemm_bf16: qkv[b][o][n] = w_qkv @ x   (MFMA, bf16 out)
//  4. softmax_qT: q-softmax over d, writes qT[b][n][hd] bf16 (reuses xt space)
//  5. ctx_partial: ctx_p = sum_n exp(k) * v  (k-softmax numerator, 4 n-splits) + row sums
//  6. make_wf: Wf[b] = w_out[:,h] @ (ctx/s)^T  folded weight, bf16
//  7. gemm_bf16: lin[b] = Wf[b] @ qT[b]^T + b_out  (MFMA)
//  8. gn_stats, 9. final_out (GN + residual, fp32 out)

typedef short s8v __attribute__((ext_vector_type(8)));
typedef float f32x4 __attribute__((ext_vector_type(4)));

__device__ __forceinline__ short f2bf(float f) {
  union { float f; unsigned u; } v; v.f = f;
  unsigned r = v.u + 0x7FFF + ((v.u >> 16) & 1);
  return (short)(r >> 16);
}
__device__ __forceinline__ float bf2f(short h) {
  union { unsigned u; float f; } v; v.u = ((unsigned)(unsigned short)h) << 16;
  return v.f;
}
__device__ __forceinline__ void gld16(const short* g, short* l) {
  __builtin_amdgcn_global_load_lds(
      (const __attribute__((address_space(1))) unsigned*)g,
      (__attribute__((address_space(3))) unsigned*)l, 16, 0, 0);
}

// ---------------- simple fp32 -> bf16 cast (w_qkv) ----------------------------
__global__ __launch_bounds__(256) void cast_to_bf16(
    const float* __restrict__ src, short* __restrict__ dst, int n8) {
  int id = blockIdx.x * 256 + threadIdx.x;
  if (id >= n8) return;
  long off = (long)id * 8;
  float4 a = *(const float4*)&src[off];
  float4 b = *(const float4*)&src[off + 4];
  s8v o;
  o[0] = f2bf(a.x); o[1] = f2bf(a.y); o[2] = f2bf(a.z); o[3] = f2bf(a.w);
  o[4] = f2bf(b.x); o[5] = f2bf(b.y); o[6] = f2bf(b.z); o[7] = f2bf(b.w);
  *(s8v*)&dst[off] = o;
}

// ---------------- x[b][c][n] fp32 -> xt[b][n][c] bf16 -------------------------
__global__ __launch_bounds__(256) void cast_transpose_x(
    const float* __restrict__ x, short* __restrict__ xt) {
  int b = blockIdx.z;
  int n0 = blockIdx.x * 64, c0 = blockIdx.y * 64;
  __shared__ short ls[64][65];  // [n_local][c_local]
  int t = threadIdx.x;
  const float* xb = x + ((long)b * 256 + c0) * 4096 + n0;
  int ci = t >> 4, j4 = (t & 15) * 4;
#pragma unroll
  for (int i = 0; i < 4; ++i) {
    int cl = ci + i * 16;
    float4 v = *(const float4*)&xb[(long)cl * 4096 + j4];
    ls[j4 + 0][cl] = f2bf(v.x);
    ls[j4 + 1][cl] = f2bf(v.y);
    ls[j4 + 2][cl] = f2bf(v.z);
    ls[j4 + 3][cl] = f2bf(v.w);
  }
  __syncthreads();
  short* xtb = xt + ((long)b * 4096 + n0) * 256 + c0;
#pragma unroll
  for (int i = 0; i < 2; ++i) {
    int id = t + i * 256;
    int nl = id >> 3, c8 = (id & 7) * 8;
    s8v o;
#pragma unroll
    for (int e = 0; e < 8; ++e) o[e] = ls[nl][c8 + e];
    *(s8v*)&xtb[(long)nl * 256 + c8] = o;
  }
}

// ---------------- MFMA GEMM: C[b][o][n] = A[o][k] * Bt[b][n][k] (+bias) -------
// A row-major [M][256] bf16 (optionally batched via a_bstride),
// Bt [b][4096][256] bf16 (K contiguous), C [b][M][4096] bf16.
// 128x128 tile, BK=64, 4 waves (2x2 of 64x64), 16x16x32 MFMA.
// LDS staged via global_load_lds (linear dest) with XOR-swizzled k-chunks:
// phys_kchunk = log_kchunk ^ (row & 7); source pre-swizzled, read swizzled.
__global__ __launch_bounds__(256) void gemm_bf16(
    const short* __restrict__ A, const short* __restrict__ Bt,
    short* __restrict__ C, const float* __restrict__ bias,
    long a_bstride, int M) {
  __shared__ short lA[128 * 64];
  __shared__ short lB[128 * 64];
  int b = blockIdx.z;
  int mt = blockIdx.y * 128, nt = blockIdx.x * 128;
  int tid = threadIdx.x;
  int lane = tid & 63;
  int wm = tid >> 7, wn = (tid >> 6) & 1;
  const short* Ab = A + (long)b * a_bstride + (long)mt * 256;
  const short* Bb = Bt + ((long)b * 4096 + nt) * 256;
  short* Cb = C + ((long)b * M + mt) * 4096 + nt;

  f32x4 acc[4][4];
#pragma unroll
  for (int i = 0; i < 4; ++i)
#pragma unroll
    for (int j = 0; j < 4; ++j) acc[i][j] = (f32x4){0.f, 0.f, 0.f, 0.f};

  for (int k0 = 0; k0 < 256; k0 += 64) {
#pragma unroll
    for (int is = 0; is < 4; ++is) {
      int s = is * 256 + tid;
      int row = s >> 3, kcp = s & 7;
      int kcl = kcp ^ (row & 7);
      short* la = &lA[(is * 256 + (tid & ~63)) * 8];
      short* lb = &lB[(is * 256 + (tid & ~63)) * 8];
      gld16(Ab + (long)row * 256 + k0 + kcl * 8, la);
      gld16(Bb + (long)row * 256 + k0 + kcl * 8, lb);
    }
    asm volatile("s_waitcnt vmcnt(0)" ::: "memory");
    __syncthreads();
#pragma unroll
    for (int kw = 0; kw < 2; ++kw) {
      int kc = kw * 4 + (lane >> 4);
      int rl = lane & 15;
      s8v av[4], bv[4];
#pragma unroll
      for (int mi = 0; mi < 4; ++mi) {
        int row = wm * 64 + mi * 16 + rl;
        av[mi] = *(const s8v*)&lA[row * 64 + ((kc ^ (row & 7)) << 3)];
      }
#pragma unroll
      for (int ni = 0; ni < 4; ++ni) {
        int row = wn * 64 + ni * 16 + rl;
        bv[ni] = *(const s8v*)&lB[row * 64 + ((kc ^ (row & 7)) << 3)];
      }
#pragma unroll
      for (int mi = 0; mi < 4; ++mi)
#pragma unroll
        for (int ni = 0; ni < 4; ++ni)
          acc[mi][ni] = __builtin_amdgcn_mfma_f32_16x16x32_bf16(
              av[mi], bv[ni], acc[mi][ni], 0, 0, 0);
    }
    __syncthreads();
  }
#pragma unroll
  for (int mi = 0; mi < 4; ++mi) {
#pragma unroll
    for (int r = 0; r < 4; ++r) {
      int o = wm * 64 + mi * 16 + (lane >> 4) * 4 + r;
      float bvv = bias ? bias[mt + o] : 0.f;
#pragma unroll
      for (int ni = 0; ni < 4; ++ni) {
        int n = wn * 64 + ni * 16 + (lane & 15);
        Cb[(long)o * 4096 + n] = f2bf(acc[mi][ni][r] + bvv);
      }
    }
  }
}

// ---------------- q softmax over d, write transposed qT[b][n][hd] -------------
__global__ __launch_bounds__(256) void softmax_qT(
    const short* __restrict__ qkv, short* __restrict__ qt) {
  int n = blockIdx.x * 256 + threadIdx.x;
  int h = blockIdx.y, b = blockIdx.z;
  const short* qb = qkv + ((long)b * 768 + h * 32) * 4096 + n;
  float v[32];
  float m = -1e30f;
#pragma unroll
  for (int d = 0; d < 32; ++d) { v[d] = bf2f(qb[(long)d * 4096]); m = fmaxf(m, v[d]); }
  float s = 0.f;
#pragma unroll
  for (int d = 0; d < 32; ++d) { v[d] = __expf(v[d] - m); s += v[d]; }
  float inv = 1.f / s;
  short* dst = qt + ((long)b * 4096 + n) * 256 + h * 32;
#pragma unroll
  for (int c8 = 0; c8 < 4; ++c8) {
    s8v o;
#pragma unroll
    for (int e = 0; e < 8; ++e) o[e] = f2bf(v[c8 * 8 + e] * inv);
    *(s8v*)&dst[c8 * 8] = o;
  }
}

// ---------------- ctx partial: sum_n exp(k[d][n]) v[e][n], + sum_n exp(k) -----
__global__ __launch_bounds__(256) void ctx_partial(
    const short* __restrict__ qkv, float* __restrict__ ctxp, float* __restrict__ sp) {
  int split = blockIdx.x;
  int h = blockIdx.y, b = blockIdx.z;
  const short* kb = qkv + ((long)(b * 768 + 256) + h * 32) * 4096;
  const short* vb = kb + (long)256 * 4096;
  __shared__ float ks[32][129];   // [d][n_local], exp applied
  __shared__ float vs[128][40];   // [n_local][e], 16B-aligned rows
  int t = threadIdx.x;
  int d = t >> 3, eq = t & 7;
  float acc0 = 0, acc1 = 0, acc2 = 0, acc3 = 0, s = 0;
  for (int n0 = split * 1024; n0 < split * 1024 + 1024; n0 += 128) {
#pragma unroll
    for (int i = 0; i < 2; ++i) {
      int id = t + i * 256;
      int row = id >> 4, c8 = (id & 15) * 8;
      s8v kv8 = *(const s8v*)&kb[(long)row * 4096 + n0 + c8];
      s8v vv8 = *(const s8v*)&vb[(long)row * 4096 + n0 + c8];
#pragma unroll
      for (int e = 0; e < 8; ++e) {
        ks[row][c8 + e] = __expf(bf2f(kv8[e]));
        vs[c8 + e][row] = bf2f(vv8[e]);
      }
    }
    __syncthreads();
#pragma unroll 4
    for (int nn = 0; nn < 128; ++nn) {
      float kv = ks[d][nn];
      float4 vv = *(const float4*)&vs[nn][eq * 4];
      acc0 += kv * vv.x; acc1 += kv * vv.y; acc2 += kv * vv.z; acc3 += kv * vv.w;
      if (eq == 0) s += kv;
    }
    __syncthreads();
  }
  long base = (long)(b * 8 + h) * 4 + split;
  float* dst = ctxp + base * 1024 + d * 32 + eq * 4;
  dst[0] = acc0; dst[1] = acc1; dst[2] = acc2; dst[3] = acc3;
  if (eq == 0) sp[base * 32 + d] = s;
}

// ---------------- Wf[b][o][h*32+d] = sum_e w_out[o][h*32+e] * ctx[d][e]/s_d ---
__global__ __launch_bounds__(256) void make_wf(
    const float* __restrict__ ctxp, const float* __restrict__ sp,
    const float* __restrict__ w_out, short* __restrict__ wf) {
  int h = blockIdx.x, b = blockIdx.y;
  __shared__ float c[32][33];
  __shared__ float inv_s[32];
  __shared__ float wv[256][33];
  int t = threadIdx.x;
  long base = (long)(b * 8 + h) * 4;
#pragma unroll
  for (int i = 0; i < 4; ++i) {
    int id = t + i * 256;
    float v = ctxp[base * 1024 + id] + ctxp[(base + 1) * 1024 + id] +
              ctxp[(base + 2) * 1024 + id] + ctxp[(base + 3) * 1024 + id];
    c[id >> 5][id & 31] = v;
  }
  if (t < 32) {
    float sv = sp[base * 32 + t] + sp[(base + 1) * 32 + t] +
               sp[(base + 2) * 32 + t] + sp[(base + 3) * 32 + t];
    inv_s[t] = 1.f / sv;
  }
#pragma unroll
  for (int r = 0; r < 32; ++r) {
    int row = r * 8 + (t >> 5);
    wv[row][t & 31] = w_out[row * 256 + h * 32 + (t & 31)];
  }
  __syncthreads();
  float wr[32];
#pragma unroll
  for (int e = 0; e < 32; ++e) wr[e] = wv[t][e];
  float tmp[32];
#pragma unroll
  for (int dd = 0; dd < 32; ++dd) {
    float sum = 0.f;
#pragma unroll
    for (int e = 0; e < 32; ++e) sum += wr[e] * c[dd][e];
    tmp[dd] = sum * inv_s[dd];
  }
  short* dst = wf + ((long)b * 256 + t) * 256 + h * 32;
#pragma unroll
  for (int c8 = 0; c8 < 4; ++c8) {
    s8v o;
#pragma unroll
    for (int e = 0; e < 8; ++e) o[e] = f2bf(tmp[c8 * 8 + e]);
    *(s8v*)&dst[c8 * 8] = o;
  }
}

// ---------------- groupnorm stats over bf16 lin --------------------------------
__global__ __launch_bounds__(256) void gn_stats(
    const short* __restrict__ lin, float2* __restrict__ stats) {
  int g = blockIdx.x, b = blockIdx.y;
  const short* base = lin + ((long)b * 256 + g * 8) * 4096;
  int t = threadIdx.x;
  float s = 0.f, ss = 0.f;
#pragma unroll
  for (int l = 0; l < 16; ++l) {
    s8v v = ((const s8v*)base)[t + l * 256];
#pragma unroll
    for (int e = 0; e < 8; ++e) { float f = bf2f(v[e]); s += f; ss += f * f; }
  }
  int wave = t >> 6, lane = t & 63;
#pragma unroll
  for (int off = 32; off >= 1; off >>= 1) { s += __shfl_xor(s, off); ss += __shfl_xor(ss, off); }
  __shared__ float rs[4], rss[4];
  if (lane == 0) { rs[wave] = s; rss[wave] = ss; }
  __syncthreads();
  if (t == 0) {
    s = rs[0] + rs[1] + rs[2] + rs[3];
    ss = rss[0] + rss[1] + rss[2] + rss[3];
    float mean = s * (1.f / 32768.f);
    float var = ss * (1.f / 32768.f) - mean * mean;
    stats[b * 32 + g] = make_float2(mean, rsqrtf(var + 1e-6f));
  }
}

// ---------------- normalize + affine + residual --------------------------------
__global__ __launch_bounds__(256) void final_out(
    const short* __restrict__ lin, const float* __restrict__ x,
    const float2* __restrict__ stats, const float* __restrict__ gamma,
    const float* __restrict__ beta, float* __restrict__ out) {
  long id = (long)blockIdx.x * 256 + threadIdx.x;
  long e0 = id * 8;
  int b = (int)(e0 >> 20);
  int rem = (int)(e0 & 1048575);
  int c = rem >> 12;
  float2 st = stats[b * 32 + (c >> 3)];
  float ga = gamma[c] * st.y;
  float be = beta[c] - st.x * ga;
  s8v l8 = *(const s8v*)&lin[e0];
  float4 x0 = *(const float4*)&x[e0];
  float4 x1 = *(const float4*)&x[e0 + 4];
  float4 o0, o1;
  o0.x = bf2f(l8[0]) * ga + be + x0.x;
  o0.y = bf2f(l8[1]) * ga + be + x0.y;
  o0.z = bf2f(l8[2]) * ga + be + x0.z;
  o0.w = bf2f(l8[3]) * ga + be + x0.w;
  o1.x = bf2f(l8[4]) * ga + be + x1.x;
  o1.y = bf2f(l8[5]) * ga + be + x1.y;
  o1.z = bf2f(l8[6]) * ga + be + x1.z;
  o1.w = bf2f(l8[7]) * ga + be + x1.w;
  *(float4*)&out[e0] = o0;
  *(float4*)&out[e0 + 4] = o1;
}

extern "C" void kernel_launch(void* const* d_in, const int* in_sizes, int n_in,
                              void* d_out, int out_size, void* d_ws, size_t ws_size,
                              hipStream_t stream) {
  const float* x     = (const float*)d_in[0];
  const float* w_qkv = (const float*)d_in[1];
  const float* w_out = (const float*)d_in[2];
  const float* b_out = (const float*)d_in[3];
  const float* gamma = (const float*)d_in[4];
  const float* beta  = (const float*)d_in[5];
  float* out = (float*)d_out;

  // workspace (shorts unless noted); xt reused as qT after gemm1.
  short* xt   = (short*)d_ws;            // 16*4096*256 = 16,777,216 shorts (32MB)
  short* qkvb = xt + 16777216;           // 16*768*4096 = 50,331,648 shorts (96MB)
  short* lin  = qkvb + 50331648;         // 16,777,216 shorts (32MB)
  short* wqb  = lin + 16777216;          // 196,608 shorts
  short* wfb  = wqb + 196608;            // 1,048,576 shorts (2MB)
  float* ctxp = (float*)(wfb + 1048576); // 524,288 floats (2MB)
  float* sp   = ctxp + 524288;           // 16,384 floats
  float2* stats = (float2*)(sp + 16384); // 512 float2

  cast_to_bf16<<<96, 256, 0, stream>>>(w_qkv, wqb, 24576);
  cast_transpose_x<<<dim3(64, 4, 16), 256, 0, stream>>>(x, xt);
  gemm_bf16<<<dim3(32, 6, 16), 256, 0, stream>>>(wqb, xt, qkvb, nullptr, 0, 768);
  softmax_qT<<<dim3(16, 8, 16), 256, 0, stream>>>(qkvb, xt);  // qT overwrites xt
  ctx_partial<<<dim3(4, 8, 16), 256, 0, stream>>>(qkvb, ctxp, sp);
  make_wf<<<dim3(8, 16), 256, 0, stream>>>(ctxp, sp, w_out, wfb);
  gemm_bf16<<<dim3(32, 2, 16), 256, 0, stream>>>(wfb, xt, lin, b_out, 65536, 256);
  gn_stats<<<dim3(32, 16), 256, 0, stream>>>(lin, stats);
  final_out<<<8192, 256, 0, stream>>>(lin, x, stats, gamma, beta, out);
}

// Round 3
// 157.942 us; speedup vs baseline: 4.5675x; 1.2133x over previous
//
#include <hip/hip_runtime.h>

// LinearAttention, bf16 MFMA pipeline (R3: MFMA-based context kernel).
// x:(16,256,64,64) fp32, w_qkv:(768,256), w_out:(256,256), b_out:(256), gamma/beta:(256)
// N=4096, HEADS=8, DIM_HEAD=32, groups=32.

typedef short s8v __attribute__((ext_vector_type(8)));
typedef float f32x4 __attribute__((ext_vector_type(4)));

__device__ __forceinline__ short f2bf(float f) {
  union { float f; unsigned u; } v; v.f = f;
  unsigned r = v.u + 0x7FFF + ((v.u >> 16) & 1);
  return (short)(r >> 16);
}
__device__ __forceinline__ float bf2f(short h) {
  union { unsigned u; float f; } v; v.u = ((unsigned)(unsigned short)h) << 16;
  return v.f;
}
__device__ __forceinline__ void gld16(const short* g, short* l) {
  __builtin_amdgcn_global_load_lds(
      (const __attribute__((address_space(1))) unsigned*)g,
      (__attribute__((address_space(3))) unsigned*)l, 16, 0, 0);
}

// ---------------- simple fp32 -> bf16 cast (w_qkv) ----------------------------
__global__ __launch_bounds__(256) void cast_to_bf16(
    const float* __restrict__ src, short* __restrict__ dst, int n8) {
  int id = blockIdx.x * 256 + threadIdx.x;
  if (id >= n8) return;
  long off = (long)id * 8;
  float4 a = *(const float4*)&src[off];
  float4 b = *(const float4*)&src[off + 4];
  s8v o;
  o[0] = f2bf(a.x); o[1] = f2bf(a.y); o[2] = f2bf(a.z); o[3] = f2bf(a.w);
  o[4] = f2bf(b.x); o[5] = f2bf(b.y); o[6] = f2bf(b.z); o[7] = f2bf(b.w);
  *(s8v*)&dst[off] = o;
}

// ---------------- x[b][c][n] fp32 -> xt[b][n][c] bf16 -------------------------
__global__ __launch_bounds__(256) void cast_transpose_x(
    const float* __restrict__ x, short* __restrict__ xt) {
  int b = blockIdx.z;
  int n0 = blockIdx.x * 64, c0 = blockIdx.y * 64;
  __shared__ short ls[64][65];  // [n_local][c_local]
  int t = threadIdx.x;
  const float* xb = x + ((long)b * 256 + c0) * 4096 + n0;
  int ci = t >> 4, j4 = (t & 15) * 4;
#pragma unroll
  for (int i = 0; i < 4; ++i) {
    int cl = ci + i * 16;
    float4 v = *(const float4*)&xb[(long)cl * 4096 + j4];
    ls[j4 + 0][cl] = f2bf(v.x);
    ls[j4 + 1][cl] = f2bf(v.y);
    ls[j4 + 2][cl] = f2bf(v.z);
    ls[j4 + 3][cl] = f2bf(v.w);
  }
  __syncthreads();
  short* xtb = xt + ((long)b * 4096 + n0) * 256 + c0;
#pragma unroll
  for (int i = 0; i < 2; ++i) {
    int id = t + i * 256;
    int nl = id >> 3, c8 = (id & 7) * 8;
    s8v o;
#pragma unroll
    for (int e = 0; e < 8; ++e) o[e] = ls[nl][c8 + e];
    *(s8v*)&xtb[(long)nl * 256 + c8] = o;
  }
}

// ---------------- MFMA GEMM: C[b][o][n] = A[o][k] * Bt[b][n][k] (+bias) -------
__global__ __launch_bounds__(256) void gemm_bf16(
    const short* __restrict__ A, const short* __restrict__ Bt,
    short* __restrict__ C, const float* __restrict__ bias,
    long a_bstride, int M) {
  __shared__ short lA[128 * 64];
  __shared__ short lB[128 * 64];
  int b = blockIdx.z;
  int mt = blockIdx.y * 128, nt = blockIdx.x * 128;
  int tid = threadIdx.x;
  int lane = tid & 63;
  int wm = tid >> 7, wn = (tid >> 6) & 1;
  const short* Ab = A + (long)b * a_bstride + (long)mt * 256;
  const short* Bb = Bt + ((long)b * 4096 + nt) * 256;
  short* Cb = C + ((long)b * M + mt) * 4096 + nt;

  f32x4 acc[4][4];
#pragma unroll
  for (int i = 0; i < 4; ++i)
#pragma unroll
    for (int j = 0; j < 4; ++j) acc[i][j] = (f32x4){0.f, 0.f, 0.f, 0.f};

  for (int k0 = 0; k0 < 256; k0 += 64) {
#pragma unroll
    for (int is = 0; is < 4; ++is) {
      int s = is * 256 + tid;
      int row = s >> 3, kcp = s & 7;
      int kcl = kcp ^ (row & 7);
      short* la = &lA[(is * 256 + (tid & ~63)) * 8];
      short* lb = &lB[(is * 256 + (tid & ~63)) * 8];
      gld16(Ab + (long)row * 256 + k0 + kcl * 8, la);
      gld16(Bb + (long)row * 256 + k0 + kcl * 8, lb);
    }
    asm volatile("s_waitcnt vmcnt(0)" ::: "memory");
    __syncthreads();
#pragma unroll
    for (int kw = 0; kw < 2; ++kw) {
      int kc = kw * 4 + (lane >> 4);
      int rl = lane & 15;
      s8v av[4], bv[4];
#pragma unroll
      for (int mi = 0; mi < 4; ++mi) {
        int row = wm * 64 + mi * 16 + rl;
        av[mi] = *(const s8v*)&lA[row * 64 + ((kc ^ (row & 7)) << 3)];
      }
#pragma unroll
      for (int ni = 0; ni < 4; ++ni) {
        int row = wn * 64 + ni * 16 + rl;
        bv[ni] = *(const s8v*)&lB[row * 64 + ((kc ^ (row & 7)) << 3)];
      }
#pragma unroll
      for (int mi = 0; mi < 4; ++mi)
#pragma unroll
        for (int ni = 0; ni < 4; ++ni)
          acc[mi][ni] = __builtin_amdgcn_mfma_f32_16x16x32_bf16(
              av[mi], bv[ni], acc[mi][ni], 0, 0, 0);
    }
    __syncthreads();
  }
#pragma unroll
  for (int mi = 0; mi < 4; ++mi) {
#pragma unroll
    for (int r = 0; r < 4; ++r) {
      int o = wm * 64 + mi * 16 + (lane >> 4) * 4 + r;
      float bvv = bias ? bias[mt + o] : 0.f;
#pragma unroll
      for (int ni = 0; ni < 4; ++ni) {
        int n = wn * 64 + ni * 16 + (lane & 15);
        Cb[(long)o * 4096 + n] = f2bf(acc[mi][ni][r] + bvv);
      }
    }
  }
}

// ---------------- q softmax over d, write transposed qT[b][n][hd] -------------
__global__ __launch_bounds__(256) void softmax_qT(
    const short* __restrict__ qkv, short* __restrict__ qt) {
  int n = blockIdx.x * 256 + threadIdx.x;
  int h = blockIdx.y, b = blockIdx.z;
  const short* qb = qkv + ((long)b * 768 + h * 32) * 4096 + n;
  float v[32];
  float m = -1e30f;
#pragma unroll
  for (int d = 0; d < 32; ++d) { v[d] = bf2f(qb[(long)d * 4096]); m = fmaxf(m, v[d]); }
  float s = 0.f;
#pragma unroll
  for (int d = 0; d < 32; ++d) { v[d] = __expf(v[d] - m); s += v[d]; }
  float inv = 1.f / s;
  short* dst = qt + ((long)b * 4096 + n) * 256 + h * 32;
#pragma unroll
  for (int c8 = 0; c8 < 4; ++c8) {
    s8v o;
#pragma unroll
    for (int e = 0; e < 8; ++e) o[e] = f2bf(v[c8 * 8 + e] * inv);
    *(s8v*)&dst[c8 * 8] = o;
  }
}

// ---------------- ctx via MFMA: ctx[d][e] = sum_n exp(k[d][n]) v[e][n] --------
// Fragments loaded straight from global (K-contiguous), exp in-register.
// 4 n-splits (blockIdx.x), 4 waves/block each covering 256 n.
__global__ __launch_bounds__(256) void ctx_mfma(
    const short* __restrict__ qkv, float* __restrict__ ctxp, float* __restrict__ sp) {
  int split = blockIdx.x;
  int h = blockIdx.y, b = blockIdx.z;
  int tid = threadIdx.x;
  int w = tid >> 6, l = tid & 63;
  const short* kb = qkv + ((long)(b * 768 + 256) + h * 32) * 4096;
  const short* vb = kb + (long)256 * 4096;
  int rl = l & 15, kg = l >> 4;
  int n_base = split * 1024 + w * 256;

  f32x4 acc[2][2];
#pragma unroll
  for (int i = 0; i < 2; ++i)
#pragma unroll
    for (int j = 0; j < 2; ++j) acc[i][j] = (f32x4){0.f, 0.f, 0.f, 0.f};
  float s_part0 = 0.f, s_part1 = 0.f;

#pragma unroll 2
  for (int it = 0; it < 8; ++it) {
    int n0 = n_base + it * 32 + kg * 8;
    s8v a0, a1, b0, b1;
    {
      s8v kr = *(const s8v*)&kb[(long)rl * 4096 + n0];
#pragma unroll
      for (int j = 0; j < 8; ++j) {
        float f = __expf(bf2f(kr[j]));
        s_part0 += f;
        a0[j] = f2bf(f);
      }
    }
    {
      s8v kr = *(const s8v*)&kb[(long)(16 + rl) * 4096 + n0];
#pragma unroll
      for (int j = 0; j < 8; ++j) {
        float f = __expf(bf2f(kr[j]));
        s_part1 += f;
        a1[j] = f2bf(f);
      }
    }
    b0 = *(const s8v*)&vb[(long)rl * 4096 + n0];
    b1 = *(const s8v*)&vb[(long)(16 + rl) * 4096 + n0];
    acc[0][0] = __builtin_amdgcn_mfma_f32_16x16x32_bf16(a0, b0, acc[0][0], 0, 0, 0);
    acc[0][1] = __builtin_amdgcn_mfma_f32_16x16x32_bf16(a0, b1, acc[0][1], 0, 0, 0);
    acc[1][0] = __builtin_amdgcn_mfma_f32_16x16x32_bf16(a1, b0, acc[1][0], 0, 0, 0);
    acc[1][1] = __builtin_amdgcn_mfma_f32_16x16x32_bf16(a1, b1, acc[1][1], 0, 0, 0);
  }
  // reduce denominator over the 4 k-group lanes (same rl)
  s_part0 += __shfl_xor(s_part0, 16); s_part0 += __shfl_xor(s_part0, 32);
  s_part1 += __shfl_xor(s_part1, 16); s_part1 += __shfl_xor(s_part1, 32);

  __shared__ float lctx[4][1024];
  __shared__ float lsum[4][32];
#pragma unroll
  for (int di = 0; di < 2; ++di)
#pragma unroll
    for (int ei = 0; ei < 2; ++ei)
#pragma unroll
      for (int r = 0; r < 4; ++r) {
        int row = di * 16 + kg * 4 + r;
        int col = ei * 16 + rl;
        lctx[w][row * 32 + col] = acc[di][ei][r];
      }
  if (kg == 0) { lsum[w][rl] = s_part0; lsum[w][16 + rl] = s_part1; }
  __syncthreads();
  long base = (long)(b * 8 + h) * 4 + split;
#pragma unroll
  for (int i = 0; i < 4; ++i) {
    int id = tid + i * 256;
    ctxp[base * 1024 + id] = lctx[0][id] + lctx[1][id] + lctx[2][id] + lctx[3][id];
  }
  if (tid < 32)
    sp[base * 32 + tid] = lsum[0][tid] + lsum[1][tid] + lsum[2][tid] + lsum[3][tid];
}

// ---------------- Wf[b][o][h*32+d] = sum_e w_out[o][h*32+e] * ctx[d][e]/s_d ---
__global__ __launch_bounds__(256) void make_wf(
    const float* __restrict__ ctxp, const float* __restrict__ sp,
    const float* __restrict__ w_out, short* __restrict__ wf) {
  int h = blockIdx.x, b = blockIdx.y;
  __shared__ float c[32][33];
  __shared__ float inv_s[32];
  __shared__ float wv[256][33];
  int t = threadIdx.x;
  long base = (long)(b * 8 + h) * 4;
#pragma unroll
  for (int i = 0; i < 4; ++i) {
    int id = t + i * 256;
    float v = ctxp[base * 1024 + id] + ctxp[(base + 1) * 1024 + id] +
              ctxp[(base + 2) * 1024 + id] + ctxp[(base + 3) * 1024 + id];
    c[id >> 5][id & 31] = v;
  }
  if (t < 32) {
    float sv = sp[base * 32 + t] + sp[(base + 1) * 32 + t] +
               sp[(base + 2) * 32 + t] + sp[(base + 3) * 32 + t];
    inv_s[t] = 1.f / sv;
  }
#pragma unroll
  for (int r = 0; r < 32; ++r) {
    int row = r * 8 + (t >> 5);
    wv[row][t & 31] = w_out[row * 256 + h * 32 + (t & 31)];
  }
  __syncthreads();
  float wr[32];
#pragma unroll
  for (int e = 0; e < 32; ++e) wr[e] = wv[t][e];
  float tmp[32];
#pragma unroll
  for (int dd = 0; dd < 32; ++dd) {
    float sum = 0.f;
#pragma unroll
    for (int e = 0; e < 32; ++e) sum += wr[e] * c[dd][e];
    tmp[dd] = sum * inv_s[dd];
  }
  short* dst = wf + ((long)b * 256 + t) * 256 + h * 32;
#pragma unroll
  for (int c8 = 0; c8 < 4; ++c8) {
    s8v o;
#pragma unroll
    for (int e = 0; e < 8; ++e) o[e] = f2bf(tmp[c8 * 8 + e]);
    *(s8v*)&dst[c8 * 8] = o;
  }
}

// ---------------- groupnorm stats over bf16 lin --------------------------------
__global__ __launch_bounds__(256) void gn_stats(
    const short* __restrict__ lin, float2* __restrict__ stats) {
  int g = blockIdx.x, b = blockIdx.y;
  const short* base = lin + ((long)b * 256 + g * 8) * 4096;
  int t = threadIdx.x;
  float s = 0.f, ss = 0.f;
#pragma unroll
  for (int l = 0; l < 16; ++l) {
    s8v v = ((const s8v*)base)[t + l * 256];
#pragma unroll
    for (int e = 0; e < 8; ++e) { float f = bf2f(v[e]); s += f; ss += f * f; }
  }
  int wave = t >> 6, lane = t & 63;
#pragma unroll
  for (int off = 32; off >= 1; off >>= 1) { s += __shfl_xor(s, off); ss += __shfl_xor(ss, off); }
  __shared__ float rs[4], rss[4];
  if (lane == 0) { rs[wave] = s; rss[wave] = ss; }
  __syncthreads();
  if (t == 0) {
    s = rs[0] + rs[1] + rs[2] + rs[3];
    ss = rss[0] + rss[1] + rss[2] + rss[3];
    float mean = s * (1.f / 32768.f);
    float var = ss * (1.f / 32768.f) - mean * mean;
    stats[b * 32 + g] = make_float2(mean, rsqrtf(var + 1e-6f));
  }
}

// ---------------- normalize + affine + residual --------------------------------
__global__ __launch_bounds__(256) void final_out(
    const short* __restrict__ lin, const float* __restrict__ x,
    const float2* __restrict__ stats, const float* __restrict__ gamma,
    const float* __restrict__ beta, float* __restrict__ out) {
  long id = (long)blockIdx.x * 256 + threadIdx.x;
  long e0 = id * 8;
  int b = (int)(e0 >> 20);
  int rem = (int)(e0 & 1048575);
  int c = rem >> 12;
  float2 st = stats[b * 32 + (c >> 3)];
  float ga = gamma[c] * st.y;
  float be = beta[c] - st.x * ga;
  s8v l8 = *(const s8v*)&lin[e0];
  float4 x0 = *(const float4*)&x[e0];
  float4 x1 = *(const float4*)&x[e0 + 4];
  float4 o0, o1;
  o0.x = bf2f(l8[0]) * ga + be + x0.x;
  o0.y = bf2f(l8[1]) * ga + be + x0.y;
  o0.z = bf2f(l8[2]) * ga + be + x0.z;
  o0.w = bf2f(l8[3]) * ga + be + x0.w;
  o1.x = bf2f(l8[4]) * ga + be + x1.x;
  o1.y = bf2f(l8[5]) * ga + be + x1.y;
  o1.z = bf2f(l8[6]) * ga + be + x1.z;
  o1.w = bf2f(l8[7]) * ga + be + x1.w;
  *(float4*)&out[e0] = o0;
  *(float4*)&out[e0 + 4] = o1;
}

extern "C" void kernel_launch(void* const* d_in, const int* in_sizes, int n_in,
                              void* d_out, int out_size, void* d_ws, size_t ws_size,
                              hipStream_t stream) {
  const float* x     = (const float*)d_in[0];
  const float* w_qkv = (const float*)d_in[1];
  const float* w_out = (const float*)d_in[2];
  const float* b_out = (const float*)d_in[3];
  const float* gamma = (const float*)d_in[4];
  const float* beta  = (const float*)d_in[5];
  float* out = (float*)d_out;

  short* xt   = (short*)d_ws;            // 16*4096*256 shorts (32MB), reused as qT
  short* qkvb = xt + 16777216;           // 16*768*4096 shorts (96MB)
  short* lin  = qkvb + 50331648;         // 16M shorts (32MB)
  short* wqb  = lin + 16777216;          // 196,608 shorts
  short* wfb  = wqb + 196608;            // 1M shorts (2MB)
  float* ctxp = (float*)(wfb + 1048576); // 524,288 floats (2MB)
  float* sp   = ctxp + 524288;           // 16,384 floats
  float2* stats = (float2*)(sp + 16384); // 512 float2

  cast_to_bf16<<<96, 256, 0, stream>>>(w_qkv, wqb, 24576);
  cast_transpose_x<<<dim3(64, 4, 16), 256, 0, stream>>>(x, xt);
  gemm_bf16<<<dim3(32, 6, 16), 256, 0, stream>>>(wqb, xt, qkvb, nullptr, 0, 768);
  softmax_qT<<<dim3(16, 8, 16), 256, 0, stream>>>(qkvb, xt);  // qT overwrites xt
  ctx_mfma<<<dim3(4, 8, 16), 256, 0, stream>>>(qkvb, ctxp, sp);
  make_wf<<<dim3(8, 16), 256, 0, stream>>>(ctxp, sp, w_out, wfb);
  gemm_bf16<<<dim3(32, 2, 16), 256, 0, stream>>>(wfb, xt, lin, b_out, 65536, 256);
  gn_stats<<<dim3(32, 16), 256, 0, stream>>>(lin, stats);
  final_out<<<8192, 256, 0, stream>>>(lin, x, stats, gamma, beta, out);
}